// Round 1
// baseline (682.062 us; speedup 1.0000x reference)
//
#include <hip/hip_runtime.h>

#define NK 8
#define NV 8

// ── ROUND-5: DIAGNOSTIC + ILP RESTRUCTURE ────────────────────────────────────
// dur_us(415) = 203us d_ws poison fill (visible in counters) + d_in restore
// (memcpy, invisible) + K (dpa_kernel, bounded only as <202us since it never
// makes top-5). Floor = 369MB @ 6.3TB/s = 59us. Cannot distinguish K~=107us
// (55% BW, real headroom) from K~=60us (floor, harness-bound) from current
// counters. REP=4 in-kernel repetition (idempotent; asm "memory" fence defeats
// cross-rep LICM of the NT loads) makes this dispatch >=236us so it surfaces
// in top-5 WITH its own hbm_gbps, and K = (dur_us - 308)/4.
//   kernel hbm_pct >= ~75%  -> revert REP=1 next round, declare roofline.
//   kernel hbm_pct ~= 50%   -> headroom real; diagnose via VALUBusy/Occupancy.
// Also carries the ILP restructure (tests H1 in the same round):
//   - q[0..7] preloaded once -> inner dep batches are pure k-loads,
//   - full-unroll kk under 128-VGPR cap (launch_bounds(256,4): 16 waves/CU
//     guaranteed resident, compiler emits counted vmcnt batches),
//   - V prefetched BEFORE softmax so 8 load latencies hide under exp VALU.
// ─────────────────────────────────────────────────────────────────────────────

#define REP 4  // DIAGNOSTIC ONLY — revert to 1 once kernel counters are read

typedef float vf4 __attribute__((ext_vector_type(4)));

__device__ __forceinline__ vf4 ntload4(const float* p) {
    return __builtin_nontemporal_load(reinterpret_cast<const vf4*>(p));
}
__device__ __forceinline__ void ntstore4(float* p, vf4 v) {
    __builtin_nontemporal_store(v, reinterpret_cast<vf4*>(p));
}

__global__ __launch_bounds__(256, 4) void dpa_kernel(const float* __restrict__ inp,
                                                     float* __restrict__ out) {
    constexpr int HW = 512 * 512;          // 262144, channel plane = 1MB
    constexpr int C = NK + NK * NV + NV;   // 80
    const float scale = 0.35355339059327373f; // 1/sqrt(8)

    int idx = blockIdx.x * blockDim.x + threadIdx.x;
    int b  = idx >> 16;          // HW/4 = 65536 vec4's per batch-plane
    int s4 = idx & 65535;
    const float* pin = inp + (size_t)b * C * HW + (size_t)s4 * 4;
    float* pout = out + (size_t)b * NV * HW + (size_t)s4 * 4;

    for (int rep = 0; rep < REP; ++rep) {
        // Compiler-level memory barrier: forces every rep to re-issue the NT
        // loads (defeats LICM/CSE across reps so HBM traffic really is 4x).
        asm volatile("" ::: "memory");

        // ── q preload: 8 loads, resident for the whole accumulation ──
        vf4 q[NK];
#pragma unroll
        for (int kk = 0; kk < NK; ++kk) q[kk] = ntload4(pin + (size_t)kk * HW);

        vf4 qk[NV];
#pragma unroll
        for (int v = 0; v < NV; ++v) qk[v] = (vf4)(0.f);

        // ── qk[v] = sum_k q[k]*K[k][v]; 64 k-loads, channels in ascending
        //    address order; full unroll -> scheduler batches loads freely
        //    within the 128-VGPR cap. ──
#pragma unroll
        for (int kk = 0; kk < NK; ++kk) {
#pragma unroll
            for (int v = 0; v < NV; ++v) {
                vf4 kv = ntload4(pin + (size_t)(NK + kk * NV + v) * HW);
                qk[v] = q[kk] * kv + qk[v];   // vector fma
            }
        }

        // ── V prefetch issued BEFORE the softmax VALU work: their HBM
        //    latency hides under max/exp/sum. q[] is dead here, so peak
        //    pressure stays ~<=128 VGPR. ──
        vf4 vv[NV];
#pragma unroll
        for (int v = 0; v < NV; ++v)
            vv[v] = ntload4(pin + (size_t)(NK + NK * NV + v) * HW);

        // scale
#pragma unroll
        for (int v = 0; v < NV; ++v) qk[v] *= scale;

        // componentwise max over v
        vf4 mx = qk[0];
#pragma unroll
        for (int v = 1; v < NV; ++v) {
            mx.x = fmaxf(mx.x, qk[v].x); mx.y = fmaxf(mx.y, qk[v].y);
            mx.z = fmaxf(mx.z, qk[v].z); mx.w = fmaxf(mx.w, qk[v].w);
        }

        // exp and sum (componentwise)
        vf4 sum = (vf4)(0.f);
#pragma unroll
        for (int v = 0; v < NV; ++v) {
            qk[v].x = __expf(qk[v].x - mx.x);
            qk[v].y = __expf(qk[v].y - mx.y);
            qk[v].z = __expf(qk[v].z - mx.z);
            qk[v].w = __expf(qk[v].w - mx.w);
            sum += qk[v];
        }
        vf4 inv;
        inv.x = 1.0f / sum.x; inv.y = 1.0f / sum.y;
        inv.z = 1.0f / sum.z; inv.w = 1.0f / sum.w;

        // out[b][v][h][w] = softmax * vchan
#pragma unroll
        for (int v = 0; v < NV; ++v)
            ntstore4(pout + (size_t)v * HW, qk[v] * inv * vv[v]);
    }
}

extern "C" void kernel_launch(void* const* d_in, const int* in_sizes, int n_in,
                              void* d_out, int out_size, void* d_ws, size_t ws_size,
                              hipStream_t stream) {
    const float* inp = (const float*)d_in[0];
    float* out = (float*)d_out;

    constexpr int HW = 512 * 512;
    constexpr int C = NK + NK * NV + NV; // 80
    int B = in_sizes[0] / (C * HW);      // 4

    int nThreads = B * (HW / 4);
    dim3 block(256);
    dim3 grid(nThreads / 256);
    dpa_kernel<<<grid, block, 0, stream>>>(inp, out);
}